// Round 1
// baseline (3000.831 us; speedup 1.0000x reference)
//
#include <hip/hip_runtime.h>
#include <hip/hip_fp16.h>

#define B_  32
#define L_  2048
#define H_  128
#define H2_ 256
#define V_  32000
#define NT_ (B_*L_)          // 65536 tokens
#define TOKS_PER_BLK 64      // per block in kernel A (processed 2 at a time)

// ---------------------------------------------------------------------------
// Kernel A: embed gather + FF + residual + LayerNorm + k-projection -> k_all
// grid 1024 x 256. FF weights fp16-packed in LDS (128KB); kp_w fp32 in regs.
// Processes 2 tokens per iteration (tok = half for LN phase).
// ---------------------------------------------------------------------------
__global__ __launch_bounds__(256) void ka_ff_ln_kp(
    const int*   __restrict__ seq,   const float* __restrict__ embed_w,
    const float* __restrict__ ff_w1, const float* __restrict__ ff_b1,
    const float* __restrict__ ff_w2, const float* __restrict__ ff_b2,
    const float* __restrict__ ln_g,  const float* __restrict__ ln_b,
    const float* __restrict__ kp_w,  float* __restrict__ k_all)
{
    __shared__ __half2 w1p[64][256];   // 64KB: w1p[j2][o] = (W1[o][2j2], W1[o][2j2+1])
    __shared__ __half2 w2p[128][128];  // 64KB: w2p[h*64+q][i] = (W2[i][128h+2q], W2[i][128h+2q+1])
    __shared__ float2 h2[128];         // (tok0,tok1) embed row
    __shared__ float2 y12[256];        // relu output, both tokens
    __shared__ float  p_sh[2][2][128]; // [half][tok][i]
    __shared__ float2 hln2[128];
    __shared__ float  red_sh[8];

    const int tid  = threadIdx.x;
    const int half = tid >> 7;
    const int i    = tid & 127;
    const int lane = tid & 63;
    const int wave = tid >> 6;

    // ---- stage FF weights (fp16 pairs) ----
    for (int idx = tid; idx < 64*256; idx += 256) {
        int o = idx >> 6, j2 = idx & 63;
        float2 ab = *(const float2*)(ff_w1 + o*128 + 2*j2);
        w1p[j2][o] = __floats2half2_rn(ab.x, ab.y);
    }
    for (int idx = tid; idx < 128*128; idx += 256) {
        int ii = idx >> 7, c = idx & 127;
        int hh = c >> 6, q = c & 63;
        float2 ab = *(const float2*)(ff_w2 + ii*256 + hh*128 + 2*q);
        w2p[c][ii] = __floats2half2_rn(ab.x, ab.y);
    }
    // ---- kp_w half-row in registers: thread (half,i) owns kp_w[i][64h..64h+63] ----
    float kreg[64];
    {
        const float* src = kp_w + (size_t)i*H_ + half*64;
        #pragma unroll
        for (int j4 = 0; j4 < 16; ++j4) {
            float4 v = *(const float4*)(src + j4*4);
            kreg[j4*4+0]=v.x; kreg[j4*4+1]=v.y; kreg[j4*4+2]=v.z; kreg[j4*4+3]=v.w;
        }
    }
    const float b1v = ff_b1[tid];
    const float b2v = ff_b2[i];
    const float gv  = ln_g[i];
    const float bv  = ln_b[i];
    __syncthreads();

    const int base = blockIdx.x * TOKS_PER_BLK;
    for (int it = 0; it < TOKS_PER_BLK; it += 2) {
        const int t0 = base + it;
        // ---- load embed rows for both tokens into h2 components ----
        if (tid < 64) {
            int tok = tid >> 5;                 // 0 or 1
            int l32 = tid & 31;
            int v   = seq[t0 + tok];
            float4 hv = *(const float4*)(embed_w + (size_t)v*H_ + l32*4);
            ((float*)&h2[l32*4+0])[tok] = hv.x;
            ((float*)&h2[l32*4+1])[tok] = hv.y;
            ((float*)&h2[l32*4+2])[tok] = hv.z;
            ((float*)&h2[l32*4+3])[tok] = hv.w;
        }
        __syncthreads();                        // B1
        // ---- y1 = relu(W1 h + b1), o = tid, both tokens ----
        float a0 = b1v, a1 = b1v;
        #pragma unroll
        for (int j2 = 0; j2 < 64; ++j2) {
            __half2 w = w1p[j2][tid];
            float4 hh = *(const float4*)&h2[2*j2];   // (t0[2j2],t1[2j2],t0[2j2+1],t1[2j2+1])
            float wl = __low2float(w), wh = __high2float(w);
            a0 = fmaf(wl, hh.x, a0); a0 = fmaf(wh, hh.z, a0);
            a1 = fmaf(wl, hh.y, a1); a1 = fmaf(wh, hh.w, a1);
        }
        y12[tid] = make_float2(fmaxf(a0, 0.f), fmaxf(a1, 0.f));
        __syncthreads();                        // B2
        // ---- y2 partial: thread (half,i), o in [128h,128h+128) ----
        float c0 = 0.f, c1 = 0.f;
        #pragma unroll
        for (int q = 0; q < 64; ++q) {
            __half2 w = w2p[half*64+q][i];
            float4 yy = *(const float4*)&y12[half*128 + 2*q];
            float wl = __low2float(w), wh = __high2float(w);
            c0 = fmaf(wl, yy.x, c0); c0 = fmaf(wh, yy.z, c0);
            c1 = fmaf(wl, yy.y, c1); c1 = fmaf(wh, yy.w, c1);
        }
        p_sh[half][0][i] = c0;
        p_sh[half][1][i] = c1;
        __syncthreads();                        // B3
        // ---- x + LayerNorm; this thread handles token=half, row i ----
        float x = ((const float*)&h2[i])[half] + p_sh[0][half][i] + p_sh[1][half][i] + b2v;
        {
            float s = x, s2 = x*x;
            #pragma unroll
            for (int m = 1; m <= 32; m <<= 1) {
                s  += __shfl_xor(s,  m);
                s2 += __shfl_xor(s2, m);
            }
            if (lane == 0) { red_sh[wave*2] = s; red_sh[wave*2+1] = s2; }
        }
        __syncthreads();                        // B4
        float mu  = (red_sh[half*4+0] + red_sh[half*4+2]) * (1.0f/128.0f);
        float ex2 = (red_sh[half*4+1] + red_sh[half*4+3]) * (1.0f/128.0f);
        float var = ex2 - mu*mu;
        float rstd = 1.0f / sqrtf(var + 1e-5f);
        float hln = (x - mu) * rstd * gv + bv;
        ((float*)&hln2[i])[half] = hln;
        __syncthreads();                        // B5
        // ---- k partial: thread (half,o=i): sum_j kp[i][j]*hln[j], j in [64h,64h+64) ----
        float k0 = 0.f, k1 = 0.f;
        #pragma unroll
        for (int jj = 0; jj < 64; ++jj) {
            float2 hh = hln2[half*64 + jj];
            k0 = fmaf(kreg[jj], hh.x, k0);
            k1 = fmaf(kreg[jj], hh.y, k1);
        }
        p_sh[half][0][i] = k0;
        p_sh[half][1][i] = k1;
        __syncthreads();                        // B6
        if (tid < 128) {
            k_all[(size_t)t0*H_     + i] = p_sh[0][0][i] + p_sh[1][0][i];
            k_all[(size_t)(t0+1)*H_ + i] = p_sh[0][1][i] + p_sh[1][1][i];
        }
    }
}

// ---------------------------------------------------------------------------
// Kernel C: sequential gated scan, one block per batch. M register-resident:
// thread (half,i) holds M[i][64h..64h+63]. kn never materialized:
//   vp = (M@k)*rn ; update M += (0.05*err*rn)*k
// Epilogue: read = M@q, r = read@rp_w.T + rp_b.
// ---------------------------------------------------------------------------
__global__ __launch_bounds__(256) void kc_scan(
    const float* __restrict__ k_all, const float* __restrict__ rp_w,
    const float* __restrict__ rp_b,  float* __restrict__ r_out)
{
    __shared__ float k_sh[128];
    __shared__ float p_sh[2][128];
    __shared__ float red_sh[8];
    __shared__ float read_sh[128];

    const int b    = blockIdx.x;
    const int tid  = threadIdx.x;
    const int half = tid >> 7;
    const int i    = tid & 127;
    const int lane = tid & 63;
    const int wave = tid >> 6;

    float M[64];
    #pragma unroll
    for (int jj = 0; jj < 64; ++jj) M[jj] = 0.f;

    const float* kb = k_all + (size_t)b * (L_*H_);
    float kv_next = (tid < 128) ? kb[tid] : 0.f;

    for (int t = 0; t < L_-1; ++t) {
        if (tid < 128) {
            float kv = kv_next;
            k_sh[tid] = kv;
            float s = kv*kv;
            #pragma unroll
            for (int m = 1; m <= 32; m <<= 1) s += __shfl_xor(s, m);
            if (lane == 0) red_sh[wave] = s;   // red[0],red[1]
        }
        __syncthreads();                        // B1
        if (tid < 128) kv_next = kb[(size_t)(t+1)*H_ + tid];  // prefetch (t+1<=L-1 valid)
        float nk2 = red_sh[0] + red_sh[1];
        float rn  = 1.0f / fmaxf(sqrtf(nk2), 1e-12f);
        float K[64];
        float acc = 0.f;
        #pragma unroll
        for (int j4 = 0; j4 < 16; ++j4) {
            float4 kk = *(const float4*)&k_sh[half*64 + j4*4];
            K[j4*4+0]=kk.x; K[j4*4+1]=kk.y; K[j4*4+2]=kk.z; K[j4*4+3]=kk.w;
            acc = fmaf(M[j4*4+0], kk.x, acc);
            acc = fmaf(M[j4*4+1], kk.y, acc);
            acc = fmaf(M[j4*4+2], kk.z, acc);
            acc = fmaf(M[j4*4+3], kk.w, acc);
        }
        p_sh[half][i] = acc;                    // raw M@k partial
        __syncthreads();                        // B2
        float vp  = (p_sh[0][i] + p_sh[1][i]) * rn;
        float err = k_sh[i] - vp;
        if (tid < 128) {
            float e2 = err*err;
            #pragma unroll
            for (int m = 1; m <= 32; m <<= 1) e2 += __shfl_xor(e2, m);
            if (lane == 0) red_sh[4+wave] = e2;
        }
        __syncthreads();                        // B3
        float ne2 = red_sh[4] + red_sh[5];
        if (ne2 >= 0.49f * nk2) {               // ||err|| >= 0.7||k||
            float sc = 0.05f * err * rn;        // (1-alpha)*err*kn_j = sc*K[j]
            #pragma unroll
            for (int jj = 0; jj < 64; ++jj) M[jj] = fmaf(sc, K[jj], M[jj]);
        }
    }
    // ---- q step: read = M @ q (q = last row, no normalization, no gate) ----
    if (tid < 128) k_sh[tid] = kv_next;         // row L-1 was prefetched at t=L-2
    __syncthreads();
    {
        float acc = 0.f;
        #pragma unroll
        for (int jj = 0; jj < 64; ++jj) acc = fmaf(M[jj], k_sh[half*64+jj], acc);
        p_sh[half][i] = acc;
    }
    __syncthreads();
    if (tid < 128) read_sh[i] = p_sh[0][i] + p_sh[1][i];
    __syncthreads();
    // ---- r = read @ rp_w.T + rp_b ----
    {
        float acc = 0.f;
        const float* wsrc = rp_w + (size_t)i*H_ + half*64;
        #pragma unroll 8
        for (int jj = 0; jj < 64; ++jj) acc = fmaf(wsrc[jj], read_sh[half*64+jj], acc);
        p_sh[half][i] = acc;
    }
    __syncthreads();
    if (tid < 128) r_out[b*H_ + i] = p_sh[0][i] + p_sh[1][i] + rp_b[i];
}

// ---------------------------------------------------------------------------
// Kernel D: out[b,v] = sum_h r[b,h]*out_w[v,h] + out_b[v].  125 blocks x 256.
// ---------------------------------------------------------------------------
__global__ __launch_bounds__(256) void kd_out(
    const float* __restrict__ r_in, const float* __restrict__ out_w,
    const float* __restrict__ out_b, float* __restrict__ out)
{
    __shared__ float r_sh[B_ * H_];             // 16KB
    const int tid = threadIdx.x;
    for (int idx = tid; idx < B_*H_; idx += 256) r_sh[idx] = r_in[idx];
    __syncthreads();
    const int v = blockIdx.x * 256 + tid;       // V_ = 125*256 exactly
    const float* wrow = out_w + (size_t)v * H_;
    float acc[B_];
    #pragma unroll
    for (int bb = 0; bb < B_; ++bb) acc[bb] = 0.f;
    for (int h4 = 0; h4 < H_/4; ++h4) {
        float4 w = *(const float4*)(wrow + h4*4);
        #pragma unroll
        for (int bb = 0; bb < B_; ++bb) {
            const float* rr = &r_sh[bb*H_ + h4*4];
            acc[bb] = fmaf(w.x, rr[0], acc[bb]);
            acc[bb] = fmaf(w.y, rr[1], acc[bb]);
            acc[bb] = fmaf(w.z, rr[2], acc[bb]);
            acc[bb] = fmaf(w.w, rr[3], acc[bb]);
        }
    }
    const float bias = out_b[v];
    #pragma unroll
    for (int bb = 0; bb < B_; ++bb) out[(size_t)bb*V_ + v] = acc[bb] + bias;
}

// ---------------------------------------------------------------------------
extern "C" void kernel_launch(void* const* d_in, const int* in_sizes, int n_in,
                              void* d_out, int out_size, void* d_ws, size_t ws_size,
                              hipStream_t stream)
{
    const int*   seq     = (const int*)  d_in[0];
    const float* embed_w = (const float*)d_in[1];
    const float* ff_w1   = (const float*)d_in[2];
    const float* ff_b1   = (const float*)d_in[3];
    const float* ff_w2   = (const float*)d_in[4];
    const float* ff_b2   = (const float*)d_in[5];
    const float* ln_g    = (const float*)d_in[6];
    const float* ln_b    = (const float*)d_in[7];
    const float* kp_w    = (const float*)d_in[8];
    const float* rp_w    = (const float*)d_in[9];
    const float* rp_b    = (const float*)d_in[10];
    const float* out_w   = (const float*)d_in[11];
    const float* out_b   = (const float*)d_in[12];
    float* out = (float*)d_out;

    float* k_all = (float*)d_ws;                        // 65536*128 fp32 = 33.5 MB
    float* r_buf = k_all + (size_t)NT_ * H_;            // 32*128 fp32

    ka_ff_ln_kp<<<dim3(NT_/TOKS_PER_BLK), dim3(256), 0, stream>>>(
        seq, embed_w, ff_w1, ff_b1, ff_w2, ff_b2, ln_g, ln_b, kp_w, k_all);
    kc_scan<<<dim3(B_), dim3(256), 0, stream>>>(k_all, rp_w, rp_b, r_buf);
    kd_out<<<dim3(V_/256), dim3(256), 0, stream>>>(r_buf, out_w, out_b, out);
}

// Round 3
// 1937.890 us; speedup vs baseline: 1.5485x; 1.5485x over previous
//
#include <hip/hip_runtime.h>
#include <hip/hip_fp16.h>

#define B_  32
#define L_  2048
#define H_  128
#define H2_ 256
#define V_  32000
#define NT_ (B_*L_)
#define TOKS_PER_BLK 64
#define CH_ 32                 // k-rows per staged chunk in kc_scan

// ---------------- DPP wave-reduce helpers (VALU, no LDS) --------------------
// dpp ctrl/masks must be integer-constant expressions -> template params.
template<int CTRL, int RMASK>
__device__ __forceinline__ float dpp_add(float x) {
    int v = __builtin_amdgcn_update_dpp(0, __float_as_int(x), CTRL, RMASK, 0xf, true);
    return x + __int_as_float(v);
}
// sum of all 64 lanes lands in lane 63
__device__ __forceinline__ float wave_sum63(float x) {
    x = dpp_add<0x111, 0xf>(x);   // row_shr:1
    x = dpp_add<0x112, 0xf>(x);   // row_shr:2
    x = dpp_add<0x114, 0xf>(x);   // row_shr:4
    x = dpp_add<0x118, 0xf>(x);   // row_shr:8
    x = dpp_add<0x142, 0xa>(x);   // row_bcast:15 -> rows 1,3
    x = dpp_add<0x143, 0xc>(x);   // row_bcast:31 -> row 3 (and 2)
    return x;
}
__device__ __forceinline__ float wave_allsum(float x) {
    x = wave_sum63(x);
    return __int_as_float(__builtin_amdgcn_readlane(__float_as_int(x), 63));
}
// add value from paired lane (lane ^ 1) via quad_perm [1,0,3,2]
__device__ __forceinline__ float pair_sum(float x) {
    int v = __builtin_amdgcn_update_dpp(0, __float_as_int(x), 0xB1, 0xf, 0xf, true);
    return x + __int_as_float(v);
}

// ---------------------------------------------------------------------------
// Kernel A: embed gather + FF + residual + LayerNorm + k-projection -> k_all
// w1 fp16 in LDS (64KB, 2 blocks/CU); w2 fp16 in registers; kp_w fp32 in regs.
// ---------------------------------------------------------------------------
__global__ __launch_bounds__(256, 2) void ka_ff_ln_kp(
    const int*   __restrict__ seq,   const float* __restrict__ embed_w,
    const float* __restrict__ ff_w1, const float* __restrict__ ff_b1,
    const float* __restrict__ ff_w2, const float* __restrict__ ff_b2,
    const float* __restrict__ ln_g,  const float* __restrict__ ln_b,
    const float* __restrict__ kp_w,  float* __restrict__ k_all)
{
    __shared__ __half2 w1p[64][256];   // 64KB: w1p[j2][o] = (W1[o][2j2], W1[o][2j2+1])
    __shared__ float2 h2[128];
    __shared__ float2 y12[256];
    __shared__ float  p_sh[2][2][128];
    __shared__ float2 hln2[128];
    __shared__ float  red_sh[8];

    const int tid  = threadIdx.x;
    const int half = tid >> 7;
    const int i    = tid & 127;
    const int lane = tid & 63;
    const int wave = tid >> 6;

    for (int idx = tid; idx < 64*256; idx += 256) {
        int o = idx >> 6, j2 = idx & 63;
        float2 ab = *(const float2*)(ff_w1 + o*128 + 2*j2);
        w1p[j2][o] = __floats2half2_rn(ab.x, ab.y);
    }
    // w2 row i, cols [128*half, 128*half+128) as 64 half2 in regs
    __half2 w2r[64];
    {
        const float* src = ff_w2 + (size_t)i*H2_ + half*128;
        #pragma unroll
        for (int q4 = 0; q4 < 16; ++q4) {
            float4 a = *(const float4*)(src + q4*8);
            float4 b = *(const float4*)(src + q4*8 + 4);
            w2r[q4*4+0] = __floats2half2_rn(a.x, a.y);
            w2r[q4*4+1] = __floats2half2_rn(a.z, a.w);
            w2r[q4*4+2] = __floats2half2_rn(b.x, b.y);
            w2r[q4*4+3] = __floats2half2_rn(b.z, b.w);
        }
    }
    float kreg[64];
    {
        const float* src = kp_w + (size_t)i*H_ + half*64;
        #pragma unroll
        for (int j4 = 0; j4 < 16; ++j4) {
            float4 v = *(const float4*)(src + j4*4);
            kreg[j4*4+0]=v.x; kreg[j4*4+1]=v.y; kreg[j4*4+2]=v.z; kreg[j4*4+3]=v.w;
        }
    }
    const float b1v = ff_b1[tid];
    const float b2v = ff_b2[i];
    const float gv  = ln_g[i];
    const float bv  = ln_b[i];
    __syncthreads();

    const int base = blockIdx.x * TOKS_PER_BLK;
    for (int it = 0; it < TOKS_PER_BLK; it += 2) {
        const int t0 = base + it;
        if (tid < 64) {
            int tok = tid >> 5;
            int l32 = tid & 31;
            int v   = seq[t0 + tok];
            float4 hv = *(const float4*)(embed_w + (size_t)v*H_ + l32*4);
            ((float*)&h2[l32*4+0])[tok] = hv.x;
            ((float*)&h2[l32*4+1])[tok] = hv.y;
            ((float*)&h2[l32*4+2])[tok] = hv.z;
            ((float*)&h2[l32*4+3])[tok] = hv.w;
        }
        __syncthreads();                        // B1
        float a0 = b1v, a1 = b1v;
        #pragma unroll
        for (int j2 = 0; j2 < 64; ++j2) {
            __half2 w = w1p[j2][tid];
            float4 hh = *(const float4*)&h2[2*j2];
            float wl = __low2float(w), wh = __high2float(w);
            a0 = fmaf(wl, hh.x, a0); a0 = fmaf(wh, hh.z, a0);
            a1 = fmaf(wl, hh.y, a1); a1 = fmaf(wh, hh.w, a1);
        }
        y12[tid] = make_float2(fmaxf(a0, 0.f), fmaxf(a1, 0.f));
        __syncthreads();                        // B2
        float c0 = 0.f, c1 = 0.f;
        #pragma unroll
        for (int q = 0; q < 64; ++q) {
            __half2 w = w2r[q];
            float4 yy = *(const float4*)&y12[half*128 + 2*q];
            float wl = __low2float(w), wh = __high2float(w);
            c0 = fmaf(wl, yy.x, c0); c0 = fmaf(wh, yy.z, c0);
            c1 = fmaf(wl, yy.y, c1); c1 = fmaf(wh, yy.w, c1);
        }
        p_sh[half][0][i] = c0;
        p_sh[half][1][i] = c1;
        __syncthreads();                        // B3
        float x = ((const float*)&h2[i])[half] + p_sh[0][half][i] + p_sh[1][half][i] + b2v;
        {
            float s = x, s2 = x*x;
            #pragma unroll
            for (int m = 1; m <= 32; m <<= 1) {
                s  += __shfl_xor(s,  m);
                s2 += __shfl_xor(s2, m);
            }
            if (lane == 0) { red_sh[wave*2] = s; red_sh[wave*2+1] = s2; }
        }
        __syncthreads();                        // B4
        float mu  = (red_sh[half*4+0] + red_sh[half*4+2]) * (1.0f/128.0f);
        float ex2 = (red_sh[half*4+1] + red_sh[half*4+3]) * (1.0f/128.0f);
        float var = ex2 - mu*mu;
        float rstd = 1.0f / sqrtf(var + 1e-5f);
        float hln = (x - mu) * rstd * gv + bv;
        ((float*)&hln2[i])[half] = hln;
        __syncthreads();                        // B5
        float k0 = 0.f, k1 = 0.f;
        #pragma unroll
        for (int jj = 0; jj < 64; ++jj) {
            float2 hh = hln2[half*64 + jj];
            k0 = fmaf(kreg[jj], hh.x, k0);
            k1 = fmaf(kreg[jj], hh.y, k1);
        }
        p_sh[half][0][i] = k0;
        p_sh[half][1][i] = k1;
        __syncthreads();                        // B6
        if (tid < 128) {
            k_all[(size_t)t0*H_     + i] = p_sh[0][0][i] + p_sh[1][0][i];
            k_all[(size_t)(t0+1)*H_ + i] = p_sh[0][1][i] + p_sh[1][1][i];
        }
    }
}

// ---------------------------------------------------------------------------
// Kernel C v2: sequential gated scan. 32 blocks x 256 threads (4 waves).
// Lane-pair layout: lane l of wave w owns row r = w*32 + (l>>1), half = l&1:
//   M[r][half*64 .. half*64+64) in 64 VGPRs.
// Per step: ONE barrier. vp pair-combine = 1 DPP quad add; ||k||^2 computed
// wave-redundantly (no cross-wave); ||err||^2 via DPP + 4-partial LDS combine.
// k rows staged in 32-row LDS chunks (double-buffered), register-prefetched
// 16 steps early so barriers almost never drain in-flight global loads.
// ---------------------------------------------------------------------------
__global__ __launch_bounds__(256, 1) void kc_scan(
    const float* __restrict__ k_all, const float* __restrict__ rp_w,
    const float* __restrict__ rp_b,  float* __restrict__ r_out)
{
    __shared__ __align__(16) float kch[2][CH_*H_];   // 32KB
    __shared__ __align__(16) float red[2][4];
    __shared__ __align__(16) float read_sh[128];
    __shared__ float pr_sh[2][128];

    const int b    = blockIdx.x;
    const int tid  = threadIdx.x;
    const int lane = tid & 63;
    const int wave = tid >> 6;
    const int half = lane & 1;
    const int r    = wave*32 + (lane >> 1);

    const float* kb = k_all + (size_t)b * (L_*H_);

    float M[64];
    #pragma unroll
    for (int j = 0; j < 64; ++j) M[j] = 0.f;

    // ---- stage chunk 0 directly ----
    #pragma unroll
    for (int jr = 0; jr < 4; ++jr) {
        float4 v = *(const float4*)(kb + jr*1024 + tid*4);
        *(float4*)&kch[0][jr*1024 + tid*4] = v;
    }
    float4 st[4];
    __syncthreads();

    #pragma unroll 1
    for (int t = 0; t < L_-1; ++t) {
        const int c   = t >> 5;
        const int row = t & 31;
        const int buf = c & 1;
        // ---- chunk staging: load 16 steps before the write ----
        if (row == 0 && c + 1 < L_/CH_) {
            const float* src = kb + (size_t)(c+1)*(CH_*H_);
            #pragma unroll
            for (int jr = 0; jr < 4; ++jr) st[jr] = *(const float4*)(src + jr*1024 + tid*4);
        }
        if (row == 16 && c + 1 < L_/CH_) {
            float* dst = &kch[buf^1][0];
            #pragma unroll
            for (int jr = 0; jr < 4; ++jr) *(float4*)&dst[jr*1024 + tid*4] = st[jr];
        }
        const float* krow = &kch[buf][row*H_];
        // ---- ||k||^2, wave-redundant (independent of vp chain) ----
        float2 kq = *(const float2*)(krow + (lane<<1));
        float nk2 = wave_allsum(fmaf(kq.x, kq.x, kq.y*kq.y));
        float rn  = 1.0f / fmaxf(sqrtf(nk2), 1e-12f);
        // ---- K frag + vp partial (4 independent FMA chains) ----
        float K[64];
        float a0=0.f, a1=0.f, a2=0.f, a3=0.f;
        #pragma unroll
        for (int j4 = 0; j4 < 16; ++j4) {
            float4 kk = *(const float4*)(krow + half*64 + j4*4);
            K[j4*4+0]=kk.x; K[j4*4+1]=kk.y; K[j4*4+2]=kk.z; K[j4*4+3]=kk.w;
            a0 = fmaf(M[j4*4+0], kk.x, a0);
            a1 = fmaf(M[j4*4+1], kk.y, a1);
            a2 = fmaf(M[j4*4+2], kk.z, a2);
            a3 = fmaf(M[j4*4+3], kk.w, a3);
        }
        float vp = pair_sum((a0+a1) + (a2+a3));   // full row dot, both lanes of pair
        float kr  = krow[r];
        float err = kr - vp*rn;
        // ---- ||err||^2: wave partial (rows duplicated x2), 4-wave combine ----
        float esum = wave_sum63(err*err);
        if (lane == 63) red[t&1][wave] = esum;
        __syncthreads();
        float4 rv = *(const float4*)&red[t&1][0];
        float ne2x2 = (rv.x+rv.y) + (rv.z+rv.w);  // = 2*||err||^2
        int fire = ne2x2 >= 0.98f * nk2;          // ||err|| >= 0.7||k||
        if (__builtin_amdgcn_readfirstlane(fire)) {
            float sc = 0.05f * err * rn;
            #pragma unroll
            for (int j = 0; j < 64; ++j) M[j] = fmaf(sc, K[j], M[j]);
        }
    }

    // ---- q step: read = M @ q (row L-1 lives in chunk 63 -> kch[1], row 31) ----
    {
        const float* qrow = &kch[1][31*H_];
        float a0=0.f, a1=0.f, a2=0.f, a3=0.f;
        #pragma unroll
        for (int j4 = 0; j4 < 16; ++j4) {
            float4 kk = *(const float4*)(qrow + half*64 + j4*4);
            a0 = fmaf(M[j4*4+0], kk.x, a0);
            a1 = fmaf(M[j4*4+1], kk.y, a1);
            a2 = fmaf(M[j4*4+2], kk.z, a2);
            a3 = fmaf(M[j4*4+3], kk.w, a3);
        }
        float vq = pair_sum((a0+a1) + (a2+a3));
        if (half == 0) read_sh[r] = vq;
    }
    __syncthreads();
    // ---- r = read @ rp_w.T + rp_b ----
    {
        const int o  = tid & 127;
        const int hf = tid >> 7;
        float acc = 0.f;
        #pragma unroll
        for (int j4 = 0; j4 < 16; ++j4) {
            float4 wv = *(const float4*)(rp_w + (size_t)o*H_ + hf*64 + j4*4);
            float4 rv = *(const float4*)&read_sh[hf*64 + j4*4];
            acc = fmaf(wv.x, rv.x, acc);
            acc = fmaf(wv.y, rv.y, acc);
            acc = fmaf(wv.z, rv.z, acc);
            acc = fmaf(wv.w, rv.w, acc);
        }
        pr_sh[hf][o] = acc;
    }
    __syncthreads();
    if (tid < 128) r_out[b*H_ + tid] = pr_sh[0][tid] + pr_sh[1][tid] + rp_b[tid];
}

// ---------------------------------------------------------------------------
// Kernel D: out[b,v] = sum_h r[b,h]*out_w[v,h] + out_b[v].
// ---------------------------------------------------------------------------
__global__ __launch_bounds__(256) void kd_out(
    const float* __restrict__ r_in, const float* __restrict__ out_w,
    const float* __restrict__ out_b, float* __restrict__ out)
{
    __shared__ float r_sh[B_ * H_];
    const int tid = threadIdx.x;
    for (int idx = tid; idx < B_*H_; idx += 256) r_sh[idx] = r_in[idx];
    __syncthreads();
    const int v = blockIdx.x * 256 + tid;
    const float* wrow = out_w + (size_t)v * H_;
    float acc[B_];
    #pragma unroll
    for (int bb = 0; bb < B_; ++bb) acc[bb] = 0.f;
    for (int h4 = 0; h4 < H_/4; ++h4) {
        float4 w = *(const float4*)(wrow + h4*4);
        #pragma unroll
        for (int bb = 0; bb < B_; ++bb) {
            const float* rr = &r_sh[bb*H_ + h4*4];
            acc[bb] = fmaf(w.x, rr[0], acc[bb]);
            acc[bb] = fmaf(w.y, rr[1], acc[bb]);
            acc[bb] = fmaf(w.z, rr[2], acc[bb]);
            acc[bb] = fmaf(w.w, rr[3], acc[bb]);
        }
    }
    const float bias = out_b[v];
    #pragma unroll
    for (int bb = 0; bb < B_; ++bb) out[(size_t)bb*V_ + v] = acc[bb] + bias;
}

// ---------------------------------------------------------------------------
extern "C" void kernel_launch(void* const* d_in, const int* in_sizes, int n_in,
                              void* d_out, int out_size, void* d_ws, size_t ws_size,
                              hipStream_t stream)
{
    const int*   seq     = (const int*)  d_in[0];
    const float* embed_w = (const float*)d_in[1];
    const float* ff_w1   = (const float*)d_in[2];
    const float* ff_b1   = (const float*)d_in[3];
    const float* ff_w2   = (const float*)d_in[4];
    const float* ff_b2   = (const float*)d_in[5];
    const float* ln_g    = (const float*)d_in[6];
    const float* ln_b    = (const float*)d_in[7];
    const float* kp_w    = (const float*)d_in[8];
    const float* rp_w    = (const float*)d_in[9];
    const float* rp_b    = (const float*)d_in[10];
    const float* out_w   = (const float*)d_in[11];
    const float* out_b   = (const float*)d_in[12];
    float* out = (float*)d_out;

    float* k_all = (float*)d_ws;
    float* r_buf = k_all + (size_t)NT_ * H_;

    ka_ff_ln_kp<<<dim3(NT_/TOKS_PER_BLK), dim3(256), 0, stream>>>(
        seq, embed_w, ff_w1, ff_b1, ff_w2, ff_b2, ln_g, ln_b, kp_w, k_all);
    kc_scan<<<dim3(B_), dim3(256), 0, stream>>>(k_all, rp_w, rp_b, r_buf);
    kd_out<<<dim3(V_/256), dim3(256), 0, stream>>>(r_buf, out_w, out_b, out);
}